// Round 2
// baseline (13098.216 us; speedup 1.0000x reference)
//
#include <hip/hip_runtime.h>

// GRU_781684048417 — round 7: round-6 (adaptive intra-XCD L2 fast path) with
// the inline-asm 128-bit operand fix.
//
// Round-6 failed to compile: HIP float4 is a struct, and LLVM rejects
// aggregate types as direct "v" register INPUTS to asm ("indirect register
// inputs" error).  All 128-bit asm operands now go through a clang
// ext_vector_type(4) float (first-class vector -> VGPR quad), which is
// accepted for both inputs and outputs.  Logic is otherwise identical to
// round 6:
//  - layer->blockIdx swizzle groups 12 (stack1/3) / 6 (stack2) consecutive
//    layers per XCD under the observed blockIdx%8 round-robin dispatch.
//  - one-time STALENESS PROBE per adjacent-block pair detects "shares an
//    XCD L2": producer plants A in its L2 (sc1-store A, sc0-read to
//    allocate), then sc1-stores B to memory bypassing L2.  A consumer that
//    sc0-reads stale A can ONLY have done so through a physically shared
//    L2; reading B => slow verdict.  False negatives are safe (fall back
//    to round-5 CP protocol bit-for-bit); a fast verdict cannot be forged.
//  - probe-confirmed links move ring data + flags to sc0 (L1-bypass,
//    L2-service) accesses: dwordx4-coalesced, ~150cyc RTT instead of ~1us.
//  - flag/probe slots are 256B-strided so no L2 line mixes fast(sc0,
//    cached-dirty) and slow(sc1, memory-side) writers.
//  - cross-pass buffers (seqA/B1/B2/hFinal) stay plain: dispatch
//    boundaries carry the flush/invalidate.

#define TPB 512
#define DRING 4
#define FS 64                       // ints per flag/probe slot (256 B)
#define PROBE_A 0x51CAFE77
#define PROBE_B 0x2B2B2B2B

typedef float vf4 __attribute__((ext_vector_type(4)));

__device__ __forceinline__ float sigmoid_f(float x) { return 1.0f / (1.0f + __expf(-x)); }
__device__ __forceinline__ float tanh_f(float x)    { return 1.0f - 2.0f / (__expf(2.0f * x) + 1.0f); }

// ---- coherence-point (cross-XCD) ops: relaxed agent-scope atomics ----
__device__ __forceinline__ int cp_load(const int* p) {
    return __hip_atomic_load(p, __ATOMIC_RELAXED, __HIP_MEMORY_SCOPE_AGENT);
}
__device__ __forceinline__ void cp_store(int* p, int v) {
    __hip_atomic_store(p, v, __ATOMIC_RELAXED, __HIP_MEMORY_SCOPE_AGENT);
}
__device__ __forceinline__ int cp_poll_nz(const int* p) {
    int v;
    while (!(v = cp_load(p))) __builtin_amdgcn_s_sleep(8);
    return v;
}
__device__ __forceinline__ float2 ld_remote2(const float* p) {
    unsigned long long u = __hip_atomic_load((const unsigned long long*)p,
                                             __ATOMIC_RELAXED, __HIP_MEMORY_SCOPE_AGENT);
    union { unsigned long long u; float2 f; } c; c.u = u;
    return c.f;
}
__device__ __forceinline__ void st_remote2(float* p, float a, float b) {
    union { unsigned long long u; float f[2]; } c; c.f[0] = a; c.f[1] = b;
    __hip_atomic_store((unsigned long long*)p, c.u,
                       __ATOMIC_RELAXED, __HIP_MEMORY_SCOPE_AGENT);
}

// ---- intra-XCD (shared L2) ops: sc0 = bypass L1, service at XCD L2 ----
__device__ __forceinline__ void vmwait0() { asm volatile("s_waitcnt vmcnt(0)" ::: "memory"); }
__device__ __forceinline__ int ld_l2_b32_wait(const int* p) {
    int r;
    asm volatile("global_load_dword %0, %1, off sc0\n\t"
                 "s_waitcnt vmcnt(0)"
                 : "=v"(r) : "v"(p) : "memory");
    return r;
}
__device__ __forceinline__ void st_l2_b32(int* p, int v) {
    asm volatile("global_store_dword %0, %1, off sc0" :: "v"(p), "v"(v) : "memory");
}
__device__ __forceinline__ void st_l2_f4(float* p, float4 v) {
    vf4 w; w[0] = v.x; w[1] = v.y; w[2] = v.z; w[3] = v.w;
    asm volatile("global_store_dwordx4 %0, %1, off sc0" :: "v"(p), "v"(w) : "memory");
}
// waits are INSIDE the asm blocks: results are architecturally valid when
// the asm retires, so no consumer can be hoisted above the waitcnt (rule #18).
__device__ __forceinline__ void ld_l2_2xf4(const float* p0, const float* p1,
                                           vf4& a, vf4& b) {
    asm volatile("global_load_dwordx4 %0, %2, off sc0\n\t"
                 "global_load_dwordx4 %1, %3, off sc0\n\t"
                 "s_waitcnt vmcnt(0)"
                 : "=&v"(a), "=&v"(b)
                 : "v"(p0), "v"(p1)
                 : "memory");
}
__device__ __forceinline__ void ld_l2_4xf4(const float* p0, const float* p1,
                                           const float* p2, const float* p3,
                                           vf4& a, vf4& b, vf4& c, vf4& d) {
    asm volatile("global_load_dwordx4 %0, %4, off sc0\n\t"
                 "global_load_dwordx4 %1, %5, off sc0\n\t"
                 "global_load_dwordx4 %2, %6, off sc0\n\t"
                 "global_load_dwordx4 %3, %7, off sc0\n\t"
                 "s_waitcnt vmcnt(0)"
                 : "=&v"(a), "=&v"(b), "=&v"(c), "=&v"(d)
                 : "v"(p0), "v"(p1), "v"(p2), "v"(p3)
                 : "memory");
}

__device__ __forceinline__ void wait_flag(int* fp, int tgt, bool fast) {
    if (fast) { while (ld_l2_b32_wait(fp) < tgt) __builtin_amdgcn_s_sleep(1); }
    else      { while (cp_load(fp) < tgt)        __builtin_amdgcn_s_sleep(2); }
}

struct PassArgs {
    const float* wih0; const float* bih0; const float* whh0; const float* bhh0;
    const float* wihA; const float* bihA; const float* whhA; const float* bhhA;
    int firstLayer;
    int NL;
    const float* seqIn;
    long seqTs;
    float* seqOut;
    float* hFinal;
    float* rings;            // [192][DRING][4096]
    int* done;               // [192][FS]
    int* prb;                // [192][FS] probe slots: [0]=val [1]=ready [2]=verdict
};

template<int STACK>
__global__ __launch_bounds__(TPB, 2) void pass_kernel(PassArgs A)
{
    constexpr int NG    = (STACK == 2) ? 96 : 192;   // gate rows per block
    constexpr int NB    = (STACK == 2) ? 128 : 64;   // batch rows per block
    constexpr int KH    = (STACK == 2) ? 128 : 64;   // recurrent K
    constexpr int PARTS = (STACK == 2) ? 4 : 2;
    constexpr int JS    = NG / 3;
    constexpr int NGG   = NG / 6;

    __shared__ float wt_hh[KH * NG];
    __shared__ float wt_ih[((STACK == 2) ? 128 : 64) * NG];
    __shared__ float atile[64 * NB];
    __shared__ float hbuf[64 * 64];

    const int tid  = threadIdx.x;

    // layer->blockIdx swizzle: consecutive layers share an XCD under the
    // blockIdx%8 round-robin heuristic.  Pure permutation — correctness is
    // carried by the probes, not by this mapping.
    const int bidx = blockIdx.x;
    int l, part;
    if (STACK == 2) { l = 6  * (bidx & 7) + ((bidx >> 3) >> 2); part = (bidx >> 3) & 3; }
    else            { l = 12 * (bidx & 7) + ((bidx >> 3) >> 1); part = (bidx >> 3) & 1; }
    const int rb = l * PARTS + part;       // logical id: rings/flags/probe index
    const int gl = A.firstLayer + l;

    const int gg = tid & (NGG - 1);
    const int bg = tid / NGG;
    const int jl0 = 2 * gg, jl1 = 2 * gg + 1;
    const int b0 = 4 * bg;

    const float *wih, *bih, *whh, *bhh;
    int din;
    if (gl == 0) { wih = A.wih0; bih = A.bih0; whh = A.whh0; bhh = A.bhh0;
                   din = (STACK == 1) ? 3 : ((STACK == 2) ? 64 : 128); }
    else {
        const int wsz = (STACK == 2) ? 384 * 128 : 192 * 64;
        const int bs  = (STACK == 2) ? 384 : 192;
        wih = A.wihA + (size_t)(gl - 1) * wsz; bih = A.bihA + (size_t)(gl - 1) * bs;
        whh = A.whhA + (size_t)(gl - 1) * wsz; bhh = A.bhhA + (size_t)(gl - 1) * bs;
        din = (STACK == 2) ? 128 : 64;
    }
    const bool wideIH = (STACK == 3) && (gl == 0);

    auto grow = [&](int r) -> int {
        if (STACK == 2) return (r >> 5) * 128 + 32 * part + (r & 31);
        return r;
    };

    for (int i = tid; i < NG * KH; i += TPB) {
        int r = i / KH, k = i - r * KH;
        wt_hh[k * NG + r] = whh[(size_t)grow(r) * KH + k];
    }
    if (!wideIH) {
        constexpr int KI = (STACK == 2) ? 128 : 64;
        for (int i = tid; i < NG * KI; i += TPB) {
            int r = i / KI, k = i - r * KI;
            wt_ih[k * NG + r] = (k < din) ? wih[(size_t)grow(r) * din + k] : 0.0f;
        }
    }

    float bR[2], bZ[2], bNH[2], bNI[2];
#pragma unroll
    for (int jj = 0; jj < 2; ++jj) {
        int jl = jl0 + jj;
        bR[jj]  = bhh[grow(jl)]          + bih[grow(jl)];
        bZ[jj]  = bhh[grow(JS + jl)]     + bih[grow(JS + jl)];
        bNH[jj] = bhh[grow(2 * JS + jl)];
        bNI[jj] = bih[grow(2 * JS + jl)];
    }

    float hprev[2][4];
#pragma unroll
    for (int jj = 0; jj < 2; ++jj)
#pragma unroll
        for (int bb = 0; bb < 4; ++bb) hprev[jj][bb] = 0.0f;

    // ---------------- one-time L2-sharing probes + link modes ----------------
    bool f_in = false, f_out = false, f_fl_self = false, f_fl_par = false, f_fl_child = false;
    {
        int* hsk = (int*)atile;          // scratch; atile unused until t-loop
        const int NL = A.NL;
        if (STACK != 2) {
            // pair (l, l+1) same part; probe slot index = producer rb.
            if (tid == 0 && l < NL - 1) {                        // producer
                int* rg = A.prb + (size_t)rb * FS;
                cp_store(rg, PROBE_A); vmwait0();
                (void)ld_l2_b32_wait(rg);                        // allocate A in my L2
                cp_store(rg, PROBE_B); vmwait0();                // memory := B, L2 keeps A
                cp_store(rg + 1, 1);                             // ready
            }
            if (tid == 1 && l > 0) {                             // consumer of pair (l-1,l)
                int* rg = A.prb + (size_t)((l - 1) * PARTS + part) * FS;
                (void)cp_poll_nz(rg + 1);
                int v = ld_l2_b32_wait(rg);
                cp_store(rg + 2, (v == PROBE_A) ? 2 : 1);        // A => shared L2
            }
            if (tid >= 8 && tid < 12) {                          // gather PP(l-2..l+1)
                int j = l - 2 + (tid - 8);
                hsk[tid - 8] = (j >= 0 && j < NL - 1)
                    ? cp_poll_nz(A.prb + (size_t)(j * PARTS + part) * FS + 2) : 0;
            }
        } else {
            // sibling probes (l,0)->(l,p) at slot l*4+p (p=1..3);
            // inter-layer probe (l,0)->(l+1,0) at slot l*4+0.
            if (part == 0 && tid < 4 && (tid > 0 || l < NL - 1)) {
                int* rg = A.prb + (size_t)(l * 4 + tid) * FS;
                cp_store(rg, PROBE_A); vmwait0();
                (void)ld_l2_b32_wait(rg);
                cp_store(rg, PROBE_B); vmwait0();
                cp_store(rg + 1, 1);
            }
            if (tid == 4 && (part != 0 || l > 0)) {
                int* rg = (part != 0) ? A.prb + (size_t)(l * 4 + part) * FS
                                      : A.prb + (size_t)((l - 1) * 4) * FS;
                (void)cp_poll_nz(rg + 1);
                int v = ld_l2_b32_wait(rg);
                cp_store(rg + 2, (v == PROBE_A) ? 2 : 1);
            }
            if (tid >= 8 && tid < 28) {                          // layers l-2..l+2 x parts
                int q = tid - 8, r = q >> 2, p = q & 3;
                int a = l - 2 + r;
                bool valid = (a >= 0 && a < NL) && (p > 0 || a < NL - 1);
                hsk[q] = valid ? cp_poll_nz(A.prb + (size_t)(a * 4 + p) * FS + 2) : 0;
            }
        }
        __syncthreads();
        if (STACK != 2) {
            const int NLl = A.NL;
            bool pp0 = hsk[0] == 2, pp1 = hsk[1] == 2, pp2 = hsk[2] == 2, pp3 = hsk[3] == 2;
            f_in       = (l > 0) && pp1;
            f_out      = (l == NLl - 1) || pp2;
            f_fl_self  = (l == 0 || pp1) && (l == NLl - 1 || pp2);
            f_fl_par   = (l > 0) && pp1 && (l < 2 || pp0);
            f_fl_child = (l < NLl - 1) && pp2 && (l + 2 >= NLl || pp3);
        } else {
            const int NLl = A.NL;
            bool S[5], T[4];
#pragma unroll
            for (int r = 0; r < 5; ++r)
                S[r] = hsk[r * 4 + 1] == 2 && hsk[r * 4 + 2] == 2 && hsk[r * 4 + 3] == 2;
#pragma unroll
            for (int r = 0; r < 4; ++r) T[r] = hsk[r * 4 + 0] == 2;
            f_out      = S[2] && (l == NLl - 1 || (S[3] && T[2]));
            f_in       = (l > 0) && S[1] && S[2] && T[1];
            f_fl_self  = S[2] && (l == 0 || (S[1] && T[1])) && (l == NLl - 1 || (S[3] && T[2]));
            f_fl_par   = (l > 0) && S[1] && S[2] && T[1] && (l < 2 || (S[0] && T[0]));
            f_fl_child = (l < NLl - 1) && S[2] && S[3] && T[2] && (l + 2 >= NLl || (S[4] && T[3]));
        }
        __syncthreads();
    }

    auto gemm64 = [&](const float* wt, const float* at, int astride,
                      float (&accR)[2][4], float (&accZ)[2][4], float (&accN)[2][4]) {
#pragma unroll 4
        for (int k = 0; k < 64; ++k) {
            const float* wr = wt + k * NG;
            float2 wR = *(const float2*)&wr[jl0];
            float2 wZ = *(const float2*)&wr[JS + jl0];
            float2 wN = *(const float2*)&wr[2 * JS + jl0];
            float4 av = *(const float4*)(at + k * astride + b0);
            float a[4] = {av.x, av.y, av.z, av.w};
#pragma unroll
            for (int bb = 0; bb < 4; ++bb) {
                accR[0][bb] += wR.x * a[bb];  accR[1][bb] += wR.y * a[bb];
                accZ[0][bb] += wZ.x * a[bb];  accZ[1][bb] += wZ.y * a[bb];
                accN[0][bb] += wN.x * a[bb];  accN[1][bb] += wN.y * a[bb];
            }
        }
    };

    // STACK2 ring staging (4096 floats per kt, 128-wide rows)
    auto stage2_fast = [&](int baseBlk, int slotT, int kt) {
        const float* p[4];
#pragma unroll
        for (int q = 0; q < 4; ++q) {
            int u4 = tid + q * TPB, r = u4 >> 5, c4 = u4 & 31, kk = kt * 64 + r;
            p[q] = A.rings + ((size_t)(baseBlk + (kk >> 5)) * DRING + slotT) * 4096
                           + (kk & 31) * 128 + 4 * c4;
        }
        vf4 ta, tb, tc, td;
        ld_l2_4xf4(p[0], p[1], p[2], p[3], ta, tb, tc, td);
        {
            int u4, r, c4;
            u4 = tid;           r = u4 >> 5; c4 = u4 & 31; *(vf4*)&atile[r * 128 + 4 * c4] = ta;
            u4 = tid + TPB;     r = u4 >> 5; c4 = u4 & 31; *(vf4*)&atile[r * 128 + 4 * c4] = tb;
            u4 = tid + 2 * TPB; r = u4 >> 5; c4 = u4 & 31; *(vf4*)&atile[r * 128 + 4 * c4] = tc;
            u4 = tid + 3 * TPB; r = u4 >> 5; c4 = u4 & 31; *(vf4*)&atile[r * 128 + 4 * c4] = td;
        }
    };
    auto stage2_slow = [&](int baseBlk, int slotT, int kt) {
        for (int u = tid; u < 4096; u += TPB) {
            int r = u >> 6, c2 = u & 63, kk = kt * 64 + r;
            const float* src = A.rings
                + ((size_t)(baseBlk + (kk >> 5)) * DRING + slotT) * 4096
                + (kk & 31) * 128 + 2 * c2;
            *(float2*)&atile[r * 128 + 2 * c2] = ld_remote2(src);
        }
    };

    for (int t = 0; t < 96; ++t) {
        float accR[2][4] = {}, accZ[2][4] = {}, accNH[2][4] = {}, accNI[2][4] = {};

        if (STACK != 2) {
            // ---- hh first (own LDS state; hides parent flag RTT) ----
            if (t > 0) gemm64(wt_hh, hbuf, 64, accR, accZ, accNH);

            // ---- parent(t) + child-antidep waits ----
            if (tid < 8) {
                int grp = tid >> 2, idx = tid & 3;
                int* fp = nullptr; int tgt = 0; bool fm = false;
                if (grp == 0) { if (l > 0 && idx == part)
                                { fp = &A.done[((l - 1) * PARTS + idx) * FS]; tgt = t + 1; fm = f_fl_par; } }
                else          { if (t >= DRING && l < A.NL - 1 && idx == part)
                                { fp = &A.done[((l + 1) * PARTS + idx) * FS]; tgt = t - DRING + 1; fm = f_fl_child; } }
                if (fp) wait_flag(fp, tgt, fm);
            }
            __syncthreads();

            // ---- ih: stage + gemm ----
            const int nkt = wideIH ? 2 : 1;
            for (int kt = 0; kt < nkt; ++kt) {
                if (kt) __syncthreads();
                if (wideIH) {
                    for (int i = tid; i < 192 * 64; i += TPB) {
                        int r = i >> 6, k = i & 63;
                        wt_ih[k * NG + r] = wih[(size_t)r * 128 + kt * 64 + k];
                    }
                }
                if (l == 0) {
                    const float* src = A.seqIn + (size_t)t * A.seqTs + (size_t)kt * 64 * 128 + 64 * part;
                    for (int i = tid; i < 1024; i += TPB) {
                        int r = i >> 4, seg = i & 15;
                        *(float4*)&atile[r * 64 + seg * 4] = *(const float4*)(src + r * 128 + seg * 4);
                    }
                } else {
                    const float* slot = A.rings + ((size_t)((l - 1) * PARTS + part) * DRING + (t & 3)) * 4096;
                    if (f_in) {
                        vf4 ta, tb;
                        ld_l2_2xf4(slot + 4 * tid, slot + 4 * (tid + TPB), ta, tb);
                        *(vf4*)&atile[4 * tid] = ta;
                        *(vf4*)&atile[4 * (tid + TPB)] = tb;
                    } else {
                        for (int u = tid; u < 2048; u += TPB)
                            *(float2*)&atile[2 * u] = ld_remote2(slot + 2 * u);
                    }
                }
                __syncthreads();
                gemm64(wt_ih, atile, 64, accR, accZ, accNI);
            }
        } else {
            // ---- STACK 2: sibling wait + hh from rings ----
            if (t > 0) {
                if (tid < 4 && tid != part)
                    wait_flag(&A.done[(l * 4 + tid) * FS], t, f_fl_self);
                __syncthreads();
                for (int kt = 0; kt < 2; ++kt) {
                    if (kt) __syncthreads();
                    if (f_out) stage2_fast(l * 4, (t - 1) & 3, kt);
                    else       stage2_slow(l * 4, (t - 1) & 3, kt);
                    __syncthreads();
                    gemm64(wt_hh + kt * 64 * NG, atile, 128, accR, accZ, accNH);
                }
            }

            // ---- parent + child waits ----
            if (tid < 8) {
                int grp = tid >> 2, idx = tid & 3;
                int* fp = nullptr; int tgt = 0; bool fm = false;
                if (grp == 0) { if (l > 0) { fp = &A.done[((l - 1) * 4 + idx) * FS]; tgt = t + 1; fm = f_fl_par; } }
                else          { if (t >= DRING && l < A.NL - 1)
                                { fp = &A.done[((l + 1) * 4 + idx) * FS]; tgt = t - DRING + 1; fm = f_fl_child; } }
                if (fp) wait_flag(fp, tgt, fm);
            }
            __syncthreads();

            // ---- ih: stage + gemm ----
            const int nkt = (l == 0 && A.firstLayer == 0) ? 1 : 2;
            for (int kt = 0; kt < nkt; ++kt) {
                if (kt) __syncthreads();
                if (l == 0) {
                    const float* src = A.seqIn + (size_t)t * A.seqTs + (size_t)kt * 64 * 128;
                    for (int i = tid; i < 2048; i += TPB)
                        *(float4*)&atile[4 * i] = *(const float4*)(src + 4 * i);
                } else {
                    if (f_in) stage2_fast((l - 1) * 4, t & 3, kt);
                    else      stage2_slow((l - 1) * 4, t & 3, kt);
                }
                __syncthreads();
                gemm64(wt_ih + kt * 64 * NG, atile, 128, accR, accZ, accNI);
            }
        }

        // ---- gates + h update + publish ----
        float4 hv[2];
#pragma unroll
        for (int jj = 0; jj < 2; ++jj) {
            float* hp = (float*)&hv[jj];
#pragma unroll
            for (int bb = 0; bb < 4; ++bb) {
                float r = sigmoid_f(accR[jj][bb] + bR[jj]);
                float z = sigmoid_f(accZ[jj][bb] + bZ[jj]);
                float n = tanh_f(accNI[jj][bb] + bNI[jj] + r * (accNH[jj][bb] + bNH[jj]));
                float h = (1.0f - z) * n + z * hprev[jj][bb];
                hprev[jj][bb] = h;
                hp[bb] = h;
            }
        }
        float* slot = A.rings + ((size_t)rb * DRING + (t & 3)) * 4096;
        if (STACK == 2) {
            if (f_out) {
                st_l2_f4(&slot[jl0 * 128 + b0], hv[0]);
                st_l2_f4(&slot[jl1 * 128 + b0], hv[1]);
            } else {
                st_remote2(&slot[jl0 * 128 + b0],     hv[0].x, hv[0].y);
                st_remote2(&slot[jl0 * 128 + b0 + 2], hv[0].z, hv[0].w);
                st_remote2(&slot[jl1 * 128 + b0],     hv[1].x, hv[1].y);
                st_remote2(&slot[jl1 * 128 + b0 + 2], hv[1].z, hv[1].w);
            }
            if (A.seqOut && l == A.NL - 1) {
                *(float4*)&A.seqOut[(size_t)t * 16384 + (32 * part + jl0) * 128 + b0] = hv[0];
                *(float4*)&A.seqOut[(size_t)t * 16384 + (32 * part + jl1) * 128 + b0] = hv[1];
            }
        } else {
            if (f_out) {
                st_l2_f4(&slot[jl0 * 64 + b0], hv[0]);
                st_l2_f4(&slot[jl1 * 64 + b0], hv[1]);
            } else {
                st_remote2(&slot[jl0 * 64 + b0],     hv[0].x, hv[0].y);
                st_remote2(&slot[jl0 * 64 + b0 + 2], hv[0].z, hv[0].w);
                st_remote2(&slot[jl1 * 64 + b0],     hv[1].x, hv[1].y);
                st_remote2(&slot[jl1 * 64 + b0 + 2], hv[1].z, hv[1].w);
            }
            *(float4*)&hbuf[jl0 * 64 + b0] = hv[0];
            *(float4*)&hbuf[jl1 * 64 + b0] = hv[1];
            if (A.seqOut && l == A.NL - 1) {
                *(float4*)&A.seqOut[(size_t)t * 16384 + jl0 * 128 + 64 * part + b0] = hv[0];
                *(float4*)&A.seqOut[(size_t)t * 16384 + jl1 * 128 + 64 * part + b0] = hv[1];
            }
            if (STACK == 3 && l == A.NL - 1 && t == 95 && A.hFinal) {
                *(float4*)&A.hFinal[jl0 * 128 + 64 * part + b0] = hv[0];
                *(float4*)&A.hFinal[jl1 * 128 + 64 * part + b0] = hv[1];
            }
        }
        // explicit per-wave drain (covers the asm sc0 stores the compiler
        // doesn't track) + barrier => all ring stores visible at their
        // serialization point (shared L2 for fast links, CP for slow) before
        // the flag store below.
        vmwait0();
        __syncthreads();
        if (tid == 0) {
            if (f_fl_self) st_l2_b32(&A.done[rb * FS], t + 1);
            else           cp_store(&A.done[rb * FS], t + 1);
        }
    }
}

__global__ void xprep_kernel(const float* __restrict__ x, float* __restrict__ seqA)
{
    int i = blockIdx.x * 256 + threadIdx.x;
    if (i < 128 * 96 * 3) {
        int b = i / 288, r = i - b * 288;
        int t = r / 3, k = r - 3 * t;
        seqA[(size_t)t * 8192 + k * 128 + b] = x[i];
    }
}

__global__ __launch_bounds__(256) void head_kernel(
    const float* __restrict__ hF,
    const float* __restrict__ d1w, const float* __restrict__ d1b,
    const float* __restrict__ d2w, const float* __restrict__ d2b,
    const float* __restrict__ d3w, const float* __restrict__ d3b,
    float* __restrict__ out)
{
    const int b = blockIdx.x, tid = threadIdx.x;
    __shared__ float h1[64], h2[32];
    if (tid < 64) {
        float s = d1b[tid];
        for (int k = 0; k < 64; ++k) s += d1w[tid * 64 + k] * hF[k * 128 + b];
        h1[tid] = fmaxf(s, 0.0f);
    }
    __syncthreads();
    if (tid < 32) {
        float s = d2b[tid];
        for (int k = 0; k < 64; ++k) s += d2w[tid * 64 + k] * h1[k];
        h2[tid] = fmaxf(s, 0.0f);
    }
    __syncthreads();
    if (tid < 250) {
        float s = d3b[tid];
        for (int k = 0; k < 32; ++k) s += d3w[tid * 32 + k] * h2[k];
        out[b * 250 + tid] = fmaxf(s, 0.0f);
    }
}

extern "C" void kernel_launch(void* const* d_in, const int* in_sizes, int n_in,
                              void* d_out, int out_size, void* d_ws, size_t ws_size,
                              hipStream_t stream)
{
    const float* x       = (const float*)d_in[0];
    const float* g1_wih0 = (const float*)d_in[1];  const float* g1_bih0 = (const float*)d_in[2];
    const float* g1_whh0 = (const float*)d_in[3];  const float* g1_bhh0 = (const float*)d_in[4];
    const float* g1_wih  = (const float*)d_in[5];  const float* g1_bih  = (const float*)d_in[6];
    const float* g1_whh  = (const float*)d_in[7];  const float* g1_bhh  = (const float*)d_in[8];
    const float* g2_wih0 = (const float*)d_in[9];  const float* g2_bih0 = (const float*)d_in[10];
    const float* g2_whh0 = (const float*)d_in[11]; const float* g2_bhh0 = (const float*)d_in[12];
    const float* g2_wih  = (const float*)d_in[13]; const float* g2_bih  = (const float*)d_in[14];
    const float* g2_whh  = (const float*)d_in[15]; const float* g2_bhh  = (const float*)d_in[16];
    const float* g3_wih0 = (const float*)d_in[17]; const float* g3_bih0 = (const float*)d_in[18];
    const float* g3_whh0 = (const float*)d_in[19]; const float* g3_bhh0 = (const float*)d_in[20];
    const float* g3_wih  = (const float*)d_in[21]; const float* g3_bih  = (const float*)d_in[22];
    const float* g3_whh  = (const float*)d_in[23]; const float* g3_bhh  = (const float*)d_in[24];
    const float* d1w = (const float*)d_in[25]; const float* d1b = (const float*)d_in[26];
    const float* d2w = (const float*)d_in[27]; const float* d2b = (const float*)d_in[28];
    const float* d3w = (const float*)d_in[29]; const float* d3b = (const float*)d_in[30];

    float* wsf = (float*)d_ws;
    const size_t RINGS = (size_t)192 * DRING * 4096;
    const size_t B1SZ  = (size_t)96 * 128 * 128;
    const size_t SEQA  = (size_t)96 * 64 * 128;
    const int    SLOTN = 192 * FS;               // ints per pass (flags or probes)
    float* rings  = wsf;
    float* B1     = rings + RINGS;
    float* B2     = B1 + B1SZ;
    float* seqA   = B2 + B1SZ;
    float* hFinal = seqA + SEQA;
    int*   flags  = (int*)(hFinal + 8192);
    int*   prb    = flags + (size_t)4 * SLOTN;

    size_t zero_bytes = (B1SZ * 2 + SEQA + 8192) * sizeof(float)
                      + (size_t)8 * SLOTN * sizeof(int);
    (void)hipMemsetAsync(B1, 0, zero_bytes, stream);

    xprep_kernel<<<dim3(144), dim3(256), 0, stream>>>(x, seqA);

    PassArgs P;
    P = {g1_wih0, g1_bih0, g1_whh0, g1_bhh0, g1_wih, g1_bih, g1_whh, g1_bhh,
         0, 96, seqA, 8192, B1, nullptr, rings, flags + 0 * SLOTN, prb + 0 * SLOTN};
    pass_kernel<1><<<dim3(192), dim3(TPB), 0, stream>>>(P);

    P = {g2_wih0, g2_bih0, g2_whh0, g2_bhh0, g2_wih, g2_bih, g2_whh, g2_bhh,
         0, 48, B1, 16384, B2, nullptr, rings, flags + 1 * SLOTN, prb + 1 * SLOTN};
    pass_kernel<2><<<dim3(192), dim3(TPB), 0, stream>>>(P);

    P = {g2_wih0, g2_bih0, g2_whh0, g2_bhh0, g2_wih, g2_bih, g2_whh, g2_bhh,
         48, 48, B2, 16384, B1, nullptr, rings, flags + 2 * SLOTN, prb + 2 * SLOTN};
    pass_kernel<2><<<dim3(192), dim3(TPB), 0, stream>>>(P);

    P = {g3_wih0, g3_bih0, g3_whh0, g3_bhh0, g3_wih, g3_bih, g3_whh, g3_bhh,
         0, 96, B1, 16384, nullptr, hFinal, rings, flags + 3 * SLOTN, prb + 3 * SLOTN};
    pass_kernel<3><<<dim3(192), dim3(TPB), 0, stream>>>(P);

    head_kernel<<<dim3(128), dim3(256), 0, stream>>>(hFinal, d1w, d1b, d2w, d2b, d3w, d3b,
                                                     (float*)d_out);
}

// Round 3
// 12104.025 us; speedup vs baseline: 1.0821x; 1.0821x over previous
//
#include <hip/hip_runtime.h>

// GRU_781684048417 — round 8: k-pair-packed LDS weights (fewer, wider ds_reads).
//
// Round-7 post-mortem: L2 fast path worked (FETCH 1.18GB -> 0.18GB) but dur
// unchanged -> link time is NOT protocol RTT; it's block-internal.  Model:
// step = 19.9us, VALU 6us, and ~4096 LDS instructions/step/CU (2 gemms x 64k x
// [3 b64 + 1 b128] x 8 waves) serializing on the CU's LDS pipe (~10-12us).
//
// This round: weights packed in LDS as [k/2][gg][12] records
// (R0 R1 Z0 Z1 N0 N1 | R0' R1' Z0' Z1' N0' N1', 48B, 16B-aligned) so each
// thread reads 3x ds_read_b128 per TWO k-steps (1.5 ops/k) instead of
// 3x ds_read_b64 per k.  Per-k LDS ops 4 -> 2.5 (-37%).  Sizes unchanged.
// Protocol (probes, sc0 fast links, flags) byte-identical to round 7.

#define TPB 512
#define DRING 4
#define FS 64                       // ints per flag/probe slot (256 B)
#define PROBE_A 0x51CAFE77
#define PROBE_B 0x2B2B2B2B

typedef float vf4 __attribute__((ext_vector_type(4)));

__device__ __forceinline__ float sigmoid_f(float x) { return 1.0f / (1.0f + __expf(-x)); }
__device__ __forceinline__ float tanh_f(float x)    { return 1.0f - 2.0f / (__expf(2.0f * x) + 1.0f); }

// ---- coherence-point (cross-XCD) ops: relaxed agent-scope atomics ----
__device__ __forceinline__ int cp_load(const int* p) {
    return __hip_atomic_load(p, __ATOMIC_RELAXED, __HIP_MEMORY_SCOPE_AGENT);
}
__device__ __forceinline__ void cp_store(int* p, int v) {
    __hip_atomic_store(p, v, __ATOMIC_RELAXED, __HIP_MEMORY_SCOPE_AGENT);
}
__device__ __forceinline__ int cp_poll_nz(const int* p) {
    int v;
    while (!(v = cp_load(p))) __builtin_amdgcn_s_sleep(8);
    return v;
}
__device__ __forceinline__ float2 ld_remote2(const float* p) {
    unsigned long long u = __hip_atomic_load((const unsigned long long*)p,
                                             __ATOMIC_RELAXED, __HIP_MEMORY_SCOPE_AGENT);
    union { unsigned long long u; float2 f; } c; c.u = u;
    return c.f;
}
__device__ __forceinline__ void st_remote2(float* p, float a, float b) {
    union { unsigned long long u; float f[2]; } c; c.f[0] = a; c.f[1] = b;
    __hip_atomic_store((unsigned long long*)p, c.u,
                       __ATOMIC_RELAXED, __HIP_MEMORY_SCOPE_AGENT);
}

// ---- intra-XCD (shared L2) ops: sc0 = bypass L1, service at XCD L2 ----
__device__ __forceinline__ void vmwait0() { asm volatile("s_waitcnt vmcnt(0)" ::: "memory"); }
__device__ __forceinline__ int ld_l2_b32_wait(const int* p) {
    int r;
    asm volatile("global_load_dword %0, %1, off sc0\n\t"
                 "s_waitcnt vmcnt(0)"
                 : "=v"(r) : "v"(p) : "memory");
    return r;
}
__device__ __forceinline__ void st_l2_b32(int* p, int v) {
    asm volatile("global_store_dword %0, %1, off sc0" :: "v"(p), "v"(v) : "memory");
}
__device__ __forceinline__ void st_l2_f4(float* p, float4 v) {
    vf4 w; w[0] = v.x; w[1] = v.y; w[2] = v.z; w[3] = v.w;
    asm volatile("global_store_dwordx4 %0, %1, off sc0" :: "v"(p), "v"(w) : "memory");
}
// waits are INSIDE the asm blocks: results are architecturally valid when
// the asm retires, so no consumer can be hoisted above the waitcnt (rule #18).
__device__ __forceinline__ void ld_l2_2xf4(const float* p0, const float* p1,
                                           vf4& a, vf4& b) {
    asm volatile("global_load_dwordx4 %0, %2, off sc0\n\t"
                 "global_load_dwordx4 %1, %3, off sc0\n\t"
                 "s_waitcnt vmcnt(0)"
                 : "=&v"(a), "=&v"(b)
                 : "v"(p0), "v"(p1)
                 : "memory");
}
__device__ __forceinline__ void ld_l2_4xf4(const float* p0, const float* p1,
                                           const float* p2, const float* p3,
                                           vf4& a, vf4& b, vf4& c, vf4& d) {
    asm volatile("global_load_dwordx4 %0, %4, off sc0\n\t"
                 "global_load_dwordx4 %1, %5, off sc0\n\t"
                 "global_load_dwordx4 %2, %6, off sc0\n\t"
                 "global_load_dwordx4 %3, %7, off sc0\n\t"
                 "s_waitcnt vmcnt(0)"
                 : "=&v"(a), "=&v"(b), "=&v"(c), "=&v"(d)
                 : "v"(p0), "v"(p1), "v"(p2), "v"(p3)
                 : "memory");
}

__device__ __forceinline__ void wait_flag(int* fp, int tgt, bool fast) {
    if (fast) { while (ld_l2_b32_wait(fp) < tgt) __builtin_amdgcn_s_sleep(1); }
    else      { while (cp_load(fp) < tgt)        __builtin_amdgcn_s_sleep(2); }
}

struct PassArgs {
    const float* wih0; const float* bih0; const float* whh0; const float* bhh0;
    const float* wihA; const float* bihA; const float* whhA; const float* bhhA;
    int firstLayer;
    int NL;
    const float* seqIn;
    long seqTs;
    float* seqOut;
    float* hFinal;
    float* rings;            // [192][DRING][4096]
    int* done;               // [192][FS]
    int* prb;                // [192][FS] probe slots: [0]=val [1]=ready [2]=verdict
};

template<int STACK>
__global__ __launch_bounds__(TPB, 2) void pass_kernel(PassArgs A)
{
    constexpr int NG    = (STACK == 2) ? 96 : 192;   // gate rows per block
    constexpr int NB    = (STACK == 2) ? 128 : 64;   // batch rows per block
    constexpr int KH    = (STACK == 2) ? 128 : 64;   // recurrent K
    constexpr int KI    = (STACK == 2) ? 128 : 64;   // padded input K
    constexpr int PARTS = (STACK == 2) ? 4 : 2;
    constexpr int JS    = NG / 3;
    constexpr int NGG   = NG / 6;
    constexpr int NW    = NGG;                       // row-pair groups per gate
    constexpr int WROW  = NW * 12;                   // packed floats per k-pair

    // packed weights: [k/2][gg][12] = R0 R1 Z0 Z1 N0 N1 (k) | same (k+1)
    __shared__ __align__(16) float wt_hh[(KH / 2) * WROW];
    __shared__ __align__(16) float wt_ih[(KI / 2) * WROW];
    __shared__ __align__(16) float atile[64 * NB];
    __shared__ __align__(16) float hbuf[64 * 64];

    const int tid  = threadIdx.x;

    // layer->blockIdx swizzle: consecutive layers share an XCD under the
    // blockIdx%8 round-robin heuristic.  Pure permutation — correctness is
    // carried by the probes, not by this mapping.
    const int bidx = blockIdx.x;
    int l, part;
    if (STACK == 2) { l = 6  * (bidx & 7) + ((bidx >> 3) >> 2); part = (bidx >> 3) & 3; }
    else            { l = 12 * (bidx & 7) + ((bidx >> 3) >> 1); part = (bidx >> 3) & 1; }
    const int rb = l * PARTS + part;       // logical id: rings/flags/probe index
    const int gl = A.firstLayer + l;

    const int gg = tid & (NGG - 1);
    const int bg = tid / NGG;
    const int jl0 = 2 * gg, jl1 = 2 * gg + 1;
    const int b0 = 4 * bg;

    const float *wih, *bih, *whh, *bhh;
    int din;
    if (gl == 0) { wih = A.wih0; bih = A.bih0; whh = A.whh0; bhh = A.bhh0;
                   din = (STACK == 1) ? 3 : ((STACK == 2) ? 64 : 128); }
    else {
        const int wsz = (STACK == 2) ? 384 * 128 : 192 * 64;
        const int bs  = (STACK == 2) ? 384 : 192;
        wih = A.wihA + (size_t)(gl - 1) * wsz; bih = A.bihA + (size_t)(gl - 1) * bs;
        whh = A.whhA + (size_t)(gl - 1) * wsz; bhh = A.bhhA + (size_t)(gl - 1) * bs;
        din = (STACK == 2) ? 128 : 64;
    }
    const bool wideIH = (STACK == 3) && (gl == 0);

    auto grow = [&](int r) -> int {
        if (STACK == 2) return (r >> 5) * 128 + 32 * part + (r & 31);
        return r;
    };

    // ---- packed weight fills ----
    for (int i = tid; i < NG * KH; i += TPB) {
        int r = i / KH, k = i - r * KH;
        int g = r / JS, j = r - g * JS;
        wt_hh[(k >> 1) * WROW + (j >> 1) * 12 + (k & 1) * 6 + g * 2 + (j & 1)]
            = whh[(size_t)grow(r) * KH + k];
    }
    if (!wideIH) {
        for (int i = tid; i < NG * KI; i += TPB) {
            int r = i / KI, k = i - r * KI;
            int g = r / JS, j = r - g * JS;
            wt_ih[(k >> 1) * WROW + (j >> 1) * 12 + (k & 1) * 6 + g * 2 + (j & 1)]
                = (k < din) ? wih[(size_t)grow(r) * din + k] : 0.0f;
        }
    }

    float bR[2], bZ[2], bNH[2], bNI[2];
#pragma unroll
    for (int jj = 0; jj < 2; ++jj) {
        int jl = jl0 + jj;
        bR[jj]  = bhh[grow(jl)]          + bih[grow(jl)];
        bZ[jj]  = bhh[grow(JS + jl)]     + bih[grow(JS + jl)];
        bNH[jj] = bhh[grow(2 * JS + jl)];
        bNI[jj] = bih[grow(2 * JS + jl)];
    }

    float hprev[2][4];
#pragma unroll
    for (int jj = 0; jj < 2; ++jj)
#pragma unroll
        for (int bb = 0; bb < 4; ++bb) hprev[jj][bb] = 0.0f;

    // ---------------- one-time L2-sharing probes + link modes ----------------
    bool f_in = false, f_out = false, f_fl_self = false, f_fl_par = false, f_fl_child = false;
    {
        int* hsk = (int*)atile;          // scratch; atile unused until t-loop
        const int NL = A.NL;
        if (STACK != 2) {
            // pair (l, l+1) same part; probe slot index = producer rb.
            if (tid == 0 && l < NL - 1) {                        // producer
                int* rg = A.prb + (size_t)rb * FS;
                cp_store(rg, PROBE_A); vmwait0();
                (void)ld_l2_b32_wait(rg);                        // allocate A in my L2
                cp_store(rg, PROBE_B); vmwait0();                // memory := B, L2 keeps A
                cp_store(rg + 1, 1);                             // ready
            }
            if (tid == 1 && l > 0) {                             // consumer of pair (l-1,l)
                int* rg = A.prb + (size_t)((l - 1) * PARTS + part) * FS;
                (void)cp_poll_nz(rg + 1);
                int v = ld_l2_b32_wait(rg);
                cp_store(rg + 2, (v == PROBE_A) ? 2 : 1);        // A => shared L2
            }
            if (tid >= 8 && tid < 12) {                          // gather PP(l-2..l+1)
                int j = l - 2 + (tid - 8);
                hsk[tid - 8] = (j >= 0 && j < NL - 1)
                    ? cp_poll_nz(A.prb + (size_t)(j * PARTS + part) * FS + 2) : 0;
            }
        } else {
            // sibling probes (l,0)->(l,p) at slot l*4+p (p=1..3);
            // inter-layer probe (l,0)->(l+1,0) at slot l*4+0.
            if (part == 0 && tid < 4 && (tid > 0 || l < NL - 1)) {
                int* rg = A.prb + (size_t)(l * 4 + tid) * FS;
                cp_store(rg, PROBE_A); vmwait0();
                (void)ld_l2_b32_wait(rg);
                cp_store(rg, PROBE_B); vmwait0();
                cp_store(rg + 1, 1);
            }
            if (tid == 4 && (part != 0 || l > 0)) {
                int* rg = (part != 0) ? A.prb + (size_t)(l * 4 + part) * FS
                                      : A.prb + (size_t)((l - 1) * 4) * FS;
                (void)cp_poll_nz(rg + 1);
                int v = ld_l2_b32_wait(rg);
                cp_store(rg + 2, (v == PROBE_A) ? 2 : 1);
            }
            if (tid >= 8 && tid < 28) {                          // layers l-2..l+2 x parts
                int q = tid - 8, r = q >> 2, p = q & 3;
                int a = l - 2 + r;
                bool valid = (a >= 0 && a < NL) && (p > 0 || a < NL - 1);
                hsk[q] = valid ? cp_poll_nz(A.prb + (size_t)(a * 4 + p) * FS + 2) : 0;
            }
        }
        __syncthreads();
        if (STACK != 2) {
            const int NLl = A.NL;
            bool pp0 = hsk[0] == 2, pp1 = hsk[1] == 2, pp2 = hsk[2] == 2, pp3 = hsk[3] == 2;
            f_in       = (l > 0) && pp1;
            f_out      = (l == NLl - 1) || pp2;
            f_fl_self  = (l == 0 || pp1) && (l == NLl - 1 || pp2);
            f_fl_par   = (l > 0) && pp1 && (l < 2 || pp0);
            f_fl_child = (l < NLl - 1) && pp2 && (l + 2 >= NLl || pp3);
        } else {
            const int NLl = A.NL;
            bool S[5], T[4];
#pragma unroll
            for (int r = 0; r < 5; ++r)
                S[r] = hsk[r * 4 + 1] == 2 && hsk[r * 4 + 2] == 2 && hsk[r * 4 + 3] == 2;
#pragma unroll
            for (int r = 0; r < 4; ++r) T[r] = hsk[r * 4 + 0] == 2;
            f_out      = S[2] && (l == NLl - 1 || (S[3] && T[2]));
            f_in       = (l > 0) && S[1] && S[2] && T[1];
            f_fl_self  = S[2] && (l == 0 || (S[1] && T[1])) && (l == NLl - 1 || (S[3] && T[2]));
            f_fl_par   = (l > 0) && S[1] && S[2] && T[1] && (l < 2 || (S[0] && T[0]));
            f_fl_child = (l < NLl - 1) && S[2] && S[3] && T[2] && (l + 2 >= NLl || (S[4] && T[3]));
        }
        __syncthreads();
    }

    // packed gemm: 32 k-pairs = 64 k per call.  Per k2: 3x ds_read_b128
    // weights + 2x ds_read_b128 activations, 48 FMA.
    auto gemmP = [&](const float* wt, const float* at, int astride,
                     float (&accR)[2][4], float (&accZ)[2][4], float (&accN)[2][4]) {
#pragma unroll 2
        for (int k2 = 0; k2 < 32; ++k2) {
            const float* wr = wt + k2 * WROW + gg * 12;
            vf4 q0 = *(const vf4*)(wr);          // R0 R1 Z0 Z1   (k even)
            vf4 q1 = *(const vf4*)(wr + 4);      // N0 N1 R0' R1'
            vf4 q2 = *(const vf4*)(wr + 8);      // Z0' Z1' N0' N1' (k odd)
            const float* ar = at + (2 * k2) * astride + b0;
            float4 a0v = *(const float4*)(ar);
            float4 a1v = *(const float4*)(ar + astride);
            float a0[4] = {a0v.x, a0v.y, a0v.z, a0v.w};
            float a1[4] = {a1v.x, a1v.y, a1v.z, a1v.w};
#pragma unroll
            for (int bb = 0; bb < 4; ++bb) {
                accR[0][bb] += q0.x * a0[bb];  accR[1][bb] += q0.y * a0[bb];
                accZ[0][bb] += q0.z * a0[bb];  accZ[1][bb] += q0.w * a0[bb];
                accN[0][bb] += q1.x * a0[bb];  accN[1][bb] += q1.y * a0[bb];
                accR[0][bb] += q1.z * a1[bb];  accR[1][bb] += q1.w * a1[bb];
                accZ[0][bb] += q2.x * a1[bb];  accZ[1][bb] += q2.y * a1[bb];
                accN[0][bb] += q2.z * a1[bb];  accN[1][bb] += q2.w * a1[bb];
            }
        }
    };

    // STACK2 ring staging (4096 floats per kt, 128-wide rows)
    auto stage2_fast = [&](int baseBlk, int slotT, int kt) {
        const float* p[4];
#pragma unroll
        for (int q = 0; q < 4; ++q) {
            int u4 = tid + q * TPB, r = u4 >> 5, c4 = u4 & 31, kk = kt * 64 + r;
            p[q] = A.rings + ((size_t)(baseBlk + (kk >> 5)) * DRING + slotT) * 4096
                           + (kk & 31) * 128 + 4 * c4;
        }
        vf4 ta, tb, tc, td;
        ld_l2_4xf4(p[0], p[1], p[2], p[3], ta, tb, tc, td);
        {
            int u4, r, c4;
            u4 = tid;           r = u4 >> 5; c4 = u4 & 31; *(vf4*)&atile[r * 128 + 4 * c4] = ta;
            u4 = tid + TPB;     r = u4 >> 5; c4 = u4 & 31; *(vf4*)&atile[r * 128 + 4 * c4] = tb;
            u4 = tid + 2 * TPB; r = u4 >> 5; c4 = u4 & 31; *(vf4*)&atile[r * 128 + 4 * c4] = tc;
            u4 = tid + 3 * TPB; r = u4 >> 5; c4 = u4 & 31; *(vf4*)&atile[r * 128 + 4 * c4] = td;
        }
    };
    auto stage2_slow = [&](int baseBlk, int slotT, int kt) {
        for (int u = tid; u < 4096; u += TPB) {
            int r = u >> 6, c2 = u & 63, kk = kt * 64 + r;
            const float* src = A.rings
                + ((size_t)(baseBlk + (kk >> 5)) * DRING + slotT) * 4096
                + (kk & 31) * 128 + 2 * c2;
            *(float2*)&atile[r * 128 + 2 * c2] = ld_remote2(src);
        }
    };

    for (int t = 0; t < 96; ++t) {
        float accR[2][4] = {}, accZ[2][4] = {}, accNH[2][4] = {}, accNI[2][4] = {};

        if (STACK != 2) {
            // ---- hh first (own LDS state; hides parent flag RTT) ----
            if (t > 0) gemmP(wt_hh, hbuf, 64, accR, accZ, accNH);

            // ---- parent(t) + child-antidep waits ----
            if (tid < 8) {
                int grp = tid >> 2, idx = tid & 3;
                int* fp = nullptr; int tgt = 0; bool fm = false;
                if (grp == 0) { if (l > 0 && idx == part)
                                { fp = &A.done[((l - 1) * PARTS + idx) * FS]; tgt = t + 1; fm = f_fl_par; } }
                else          { if (t >= DRING && l < A.NL - 1 && idx == part)
                                { fp = &A.done[((l + 1) * PARTS + idx) * FS]; tgt = t - DRING + 1; fm = f_fl_child; } }
                if (fp) wait_flag(fp, tgt, fm);
            }
            __syncthreads();

            // ---- ih: stage + gemm ----
            const int nkt = wideIH ? 2 : 1;
            for (int kt = 0; kt < nkt; ++kt) {
                if (kt) __syncthreads();
                if (wideIH) {
                    for (int i = tid; i < 192 * 64; i += TPB) {
                        int r = i >> 6, k = i & 63;
                        int g = r >> 6, j = r & 63;
                        wt_ih[(k >> 1) * WROW + (j >> 1) * 12 + (k & 1) * 6 + g * 2 + (j & 1)]
                            = wih[(size_t)r * 128 + kt * 64 + k];
                    }
                }
                if (l == 0) {
                    const float* src = A.seqIn + (size_t)t * A.seqTs + (size_t)kt * 64 * 128 + 64 * part;
                    for (int i = tid; i < 1024; i += TPB) {
                        int r = i >> 4, seg = i & 15;
                        *(float4*)&atile[r * 64 + seg * 4] = *(const float4*)(src + r * 128 + seg * 4);
                    }
                } else {
                    const float* slot = A.rings + ((size_t)((l - 1) * PARTS + part) * DRING + (t & 3)) * 4096;
                    if (f_in) {
                        vf4 ta, tb;
                        ld_l2_2xf4(slot + 4 * tid, slot + 4 * (tid + TPB), ta, tb);
                        *(vf4*)&atile[4 * tid] = ta;
                        *(vf4*)&atile[4 * (tid + TPB)] = tb;
                    } else {
                        for (int u = tid; u < 2048; u += TPB)
                            *(float2*)&atile[2 * u] = ld_remote2(slot + 2 * u);
                    }
                }
                __syncthreads();
                gemmP(wt_ih, atile, 64, accR, accZ, accNI);
            }
        } else {
            // ---- STACK 2: sibling wait + hh from rings ----
            if (t > 0) {
                if (tid < 4 && tid != part)
                    wait_flag(&A.done[(l * 4 + tid) * FS], t, f_fl_self);
                __syncthreads();
                for (int kt = 0; kt < 2; ++kt) {
                    if (kt) __syncthreads();
                    if (f_out) stage2_fast(l * 4, (t - 1) & 3, kt);
                    else       stage2_slow(l * 4, (t - 1) & 3, kt);
                    __syncthreads();
                    gemmP(wt_hh + kt * 32 * WROW, atile, 128, accR, accZ, accNH);
                }
            }

            // ---- parent + child waits ----
            if (tid < 8) {
                int grp = tid >> 2, idx = tid & 3;
                int* fp = nullptr; int tgt = 0; bool fm = false;
                if (grp == 0) { if (l > 0) { fp = &A.done[((l - 1) * 4 + idx) * FS]; tgt = t + 1; fm = f_fl_par; } }
                else          { if (t >= DRING && l < A.NL - 1)
                                { fp = &A.done[((l + 1) * 4 + idx) * FS]; tgt = t - DRING + 1; fm = f_fl_child; } }
                if (fp) wait_flag(fp, tgt, fm);
            }
            __syncthreads();

            // ---- ih: stage + gemm ----
            const int nkt = (l == 0 && A.firstLayer == 0) ? 1 : 2;
            for (int kt = 0; kt < nkt; ++kt) {
                if (kt) __syncthreads();
                if (l == 0) {
                    const float* src = A.seqIn + (size_t)t * A.seqTs + (size_t)kt * 64 * 128;
                    for (int i = tid; i < 2048; i += TPB)
                        *(float4*)&atile[4 * i] = *(const float4*)(src + 4 * i);
                } else {
                    if (f_in) stage2_fast((l - 1) * 4, t & 3, kt);
                    else      stage2_slow((l - 1) * 4, t & 3, kt);
                }
                __syncthreads();
                gemmP(wt_ih + kt * 32 * WROW, atile, 128, accR, accZ, accNI);
            }
        }

        // ---- gates + h update + publish ----
        float4 hv[2];
#pragma unroll
        for (int jj = 0; jj < 2; ++jj) {
            float* hp = (float*)&hv[jj];
#pragma unroll
            for (int bb = 0; bb < 4; ++bb) {
                float r = sigmoid_f(accR[jj][bb] + bR[jj]);
                float z = sigmoid_f(accZ[jj][bb] + bZ[jj]);
                float n = tanh_f(accNI[jj][bb] + bNI[jj] + r * (accNH[jj][bb] + bNH[jj]));
                float h = (1.0f - z) * n + z * hprev[jj][bb];
                hprev[jj][bb] = h;
                hp[bb] = h;
            }
        }
        float* slot = A.rings + ((size_t)rb * DRING + (t & 3)) * 4096;
        if (STACK == 2) {
            if (f_out) {
                st_l2_f4(&slot[jl0 * 128 + b0], hv[0]);
                st_l2_f4(&slot[jl1 * 128 + b0], hv[1]);
            } else {
                st_remote2(&slot[jl0 * 128 + b0],     hv[0].x, hv[0].y);
                st_remote2(&slot[jl0 * 128 + b0 + 2], hv[0].z, hv[0].w);
                st_remote2(&slot[jl1 * 128 + b0],     hv[1].x, hv[1].y);
                st_remote2(&slot[jl1 * 128 + b0 + 2], hv[1].z, hv[1].w);
            }
            if (A.seqOut && l == A.NL - 1) {
                *(float4*)&A.seqOut[(size_t)t * 16384 + (32 * part + jl0) * 128 + b0] = hv[0];
                *(float4*)&A.seqOut[(size_t)t * 16384 + (32 * part + jl1) * 128 + b0] = hv[1];
            }
        } else {
            if (f_out) {
                st_l2_f4(&slot[jl0 * 64 + b0], hv[0]);
                st_l2_f4(&slot[jl1 * 64 + b0], hv[1]);
            } else {
                st_remote2(&slot[jl0 * 64 + b0],     hv[0].x, hv[0].y);
                st_remote2(&slot[jl0 * 64 + b0 + 2], hv[0].z, hv[0].w);
                st_remote2(&slot[jl1 * 64 + b0],     hv[1].x, hv[1].y);
                st_remote2(&slot[jl1 * 64 + b0 + 2], hv[1].z, hv[1].w);
            }
            *(float4*)&hbuf[jl0 * 64 + b0] = hv[0];
            *(float4*)&hbuf[jl1 * 64 + b0] = hv[1];
            if (A.seqOut && l == A.NL - 1) {
                *(float4*)&A.seqOut[(size_t)t * 16384 + jl0 * 128 + 64 * part + b0] = hv[0];
                *(float4*)&A.seqOut[(size_t)t * 16384 + jl1 * 128 + 64 * part + b0] = hv[1];
            }
            if (STACK == 3 && l == A.NL - 1 && t == 95 && A.hFinal) {
                *(float4*)&A.hFinal[jl0 * 128 + 64 * part + b0] = hv[0];
                *(float4*)&A.hFinal[jl1 * 128 + 64 * part + b0] = hv[1];
            }
        }
        // explicit per-wave drain (covers the asm sc0 stores the compiler
        // doesn't track) + barrier => all ring stores visible at their
        // serialization point (shared L2 for fast links, CP for slow) before
        // the flag store below.
        vmwait0();
        __syncthreads();
        if (tid == 0) {
            if (f_fl_self) st_l2_b32(&A.done[rb * FS], t + 1);
            else           cp_store(&A.done[rb * FS], t + 1);
        }
    }
}

__global__ void xprep_kernel(const float* __restrict__ x, float* __restrict__ seqA)
{
    int i = blockIdx.x * 256 + threadIdx.x;
    if (i < 128 * 96 * 3) {
        int b = i / 288, r = i - b * 288;
        int t = r / 3, k = r - 3 * t;
        seqA[(size_t)t * 8192 + k * 128 + b] = x[i];
    }
}

__global__ __launch_bounds__(256) void head_kernel(
    const float* __restrict__ hF,
    const float* __restrict__ d1w, const float* __restrict__ d1b,
    const float* __restrict__ d2w, const float* __restrict__ d2b,
    const float* __restrict__ d3w, const float* __restrict__ d3b,
    float* __restrict__ out)
{
    const int b = blockIdx.x, tid = threadIdx.x;
    __shared__ float h1[64], h2[32];
    if (tid < 64) {
        float s = d1b[tid];
        for (int k = 0; k < 64; ++k) s += d1w[tid * 64 + k] * hF[k * 128 + b];
        h1[tid] = fmaxf(s, 0.0f);
    }
    __syncthreads();
    if (tid < 32) {
        float s = d2b[tid];
        for (int k = 0; k < 64; ++k) s += d2w[tid * 64 + k] * h1[k];
        h2[tid] = fmaxf(s, 0.0f);
    }
    __syncthreads();
    if (tid < 250) {
        float s = d3b[tid];
        for (int k = 0; k < 32; ++k) s += d3w[tid * 32 + k] * h2[k];
        out[b * 250 + tid] = fmaxf(s, 0.0f);
    }
}

extern "C" void kernel_launch(void* const* d_in, const int* in_sizes, int n_in,
                              void* d_out, int out_size, void* d_ws, size_t ws_size,
                              hipStream_t stream)
{
    const float* x       = (const float*)d_in[0];
    const float* g1_wih0 = (const float*)d_in[1];  const float* g1_bih0 = (const float*)d_in[2];
    const float* g1_whh0 = (const float*)d_in[3];  const float* g1_bhh0 = (const float*)d_in[4];
    const float* g1_wih  = (const float*)d_in[5];  const float* g1_bih  = (const float*)d_in[6];
    const float* g1_whh  = (const float*)d_in[7];  const float* g1_bhh  = (const float*)d_in[8];
    const float* g2_wih0 = (const float*)d_in[9];  const float* g2_bih0 = (const float*)d_in[10];
    const float* g2_whh0 = (const float*)d_in[11]; const float* g2_bhh0 = (const float*)d_in[12];
    const float* g2_wih  = (const float*)d_in[13]; const float* g2_bih  = (const float*)d_in[14];
    const float* g2_whh  = (const float*)d_in[15]; const float* g2_bhh  = (const float*)d_in[16];
    const float* g3_wih0 = (const float*)d_in[17]; const float* g3_bih0 = (const float*)d_in[18];
    const float* g3_whh0 = (const float*)d_in[19]; const float* g3_bhh0 = (const float*)d_in[20];
    const float* g3_wih  = (const float*)d_in[21]; const float* g3_bih  = (const float*)d_in[22];
    const float* g3_whh  = (const float*)d_in[23]; const float* g3_bhh  = (const float*)d_in[24];
    const float* d1w = (const float*)d_in[25]; const float* d1b = (const float*)d_in[26];
    const float* d2w = (const float*)d_in[27]; const float* d2b = (const float*)d_in[28];
    const float* d3w = (const float*)d_in[29]; const float* d3b = (const float*)d_in[30];

    float* wsf = (float*)d_ws;
    const size_t RINGS = (size_t)192 * DRING * 4096;
    const size_t B1SZ  = (size_t)96 * 128 * 128;
    const size_t SEQA  = (size_t)96 * 64 * 128;
    const int    SLOTN = 192 * FS;               // ints per pass (flags or probes)
    float* rings  = wsf;
    float* B1     = rings + RINGS;
    float* B2     = B1 + B1SZ;
    float* seqA   = B2 + B1SZ;
    float* hFinal = seqA + SEQA;
    int*   flags  = (int*)(hFinal + 8192);
    int*   prb    = flags + (size_t)4 * SLOTN;

    size_t zero_bytes = (B1SZ * 2 + SEQA + 8192) * sizeof(float)
                      + (size_t)8 * SLOTN * sizeof(int);
    (void)hipMemsetAsync(B1, 0, zero_bytes, stream);

    xprep_kernel<<<dim3(144), dim3(256), 0, stream>>>(x, seqA);

    PassArgs P;
    P = {g1_wih0, g1_bih0, g1_whh0, g1_bhh0, g1_wih, g1_bih, g1_whh, g1_bhh,
         0, 96, seqA, 8192, B1, nullptr, rings, flags + 0 * SLOTN, prb + 0 * SLOTN};
    pass_kernel<1><<<dim3(192), dim3(TPB), 0, stream>>>(P);

    P = {g2_wih0, g2_bih0, g2_whh0, g2_bhh0, g2_wih, g2_bih, g2_whh, g2_bhh,
         0, 48, B1, 16384, B2, nullptr, rings, flags + 1 * SLOTN, prb + 1 * SLOTN};
    pass_kernel<2><<<dim3(192), dim3(TPB), 0, stream>>>(P);

    P = {g2_wih0, g2_bih0, g2_whh0, g2_bhh0, g2_wih, g2_bih, g2_whh, g2_bhh,
         48, 48, B2, 16384, B1, nullptr, rings, flags + 2 * SLOTN, prb + 2 * SLOTN};
    pass_kernel<2><<<dim3(192), dim3(TPB), 0, stream>>>(P);

    P = {g3_wih0, g3_bih0, g3_whh0, g3_bhh0, g3_wih, g3_bih, g3_whh, g3_bhh,
         0, 96, B1, 16384, nullptr, hFinal, rings, flags + 3 * SLOTN, prb + 3 * SLOTN};
    pass_kernel<3><<<dim3(192), dim3(TPB), 0, stream>>>(P);

    head_kernel<<<dim3(128), dim3(256), 0, stream>>>(hFinal, d1w, d1b, d2w, d2b, d3w, d3b,
                                                     (float*)d_out);
}

// Round 4
// 10299.760 us; speedup vs baseline: 1.2717x; 1.1752x over previous
//
#include <hip/hip_runtime.h>

// GRU_781684048417 — round 9: wide coherence-point transfers for slow links
// (pacer-block fix).
//
// Evidence trail: r7 (L2 fast path for 11/12 links) and r8 (k-pair-packed LDS,
// -37% LDS insts) moved FETCH/bank-conflict counters but p stayed ~19us.
// Pipeline throughput = max over blocks of per-step time; the XCD-BOUNDARY
// blocks still staged 16KB/step via 2048 uncoalesced 8B agent atomics (up to
// 4 stages/step on stack2) — they pace the whole wavefront.
//
// This round: slow-path ring data moves as plain global_{load,store}_dwordx4
// with sc0 sc1 (bypass L1+L2 -> serviced at the memory-side coherence point,
// the same serialization point the 8B atomics used; visibility ordering is
// carried by the existing vmcnt(0)-drain + flag protocol, validated in r4/r5).
// Slow stage/publish are now instruction-identical to the fast path except
// for cache-policy bits.  Flags stay 4B CP atomics.  Probes unchanged.

#define TPB 512
#define DRING 4
#define FS 64                       // ints per flag/probe slot (256 B)
#define PROBE_A 0x51CAFE77
#define PROBE_B 0x2B2B2B2B

typedef float vf4 __attribute__((ext_vector_type(4)));

__device__ __forceinline__ float sigmoid_f(float x) { return 1.0f / (1.0f + __expf(-x)); }
__device__ __forceinline__ float tanh_f(float x)    { return 1.0f - 2.0f / (__expf(2.0f * x) + 1.0f); }

// ---- coherence-point flag ops: relaxed agent-scope atomics ----
__device__ __forceinline__ int cp_load(const int* p) {
    return __hip_atomic_load(p, __ATOMIC_RELAXED, __HIP_MEMORY_SCOPE_AGENT);
}
__device__ __forceinline__ void cp_store(int* p, int v) {
    __hip_atomic_store(p, v, __ATOMIC_RELAXED, __HIP_MEMORY_SCOPE_AGENT);
}
__device__ __forceinline__ int cp_poll_nz(const int* p) {
    int v;
    while (!(v = cp_load(p))) __builtin_amdgcn_s_sleep(8);
    return v;
}

// ---- intra-XCD (shared L2) ops: sc0 = bypass L1, service at XCD L2 ----
__device__ __forceinline__ void vmwait0() { asm volatile("s_waitcnt vmcnt(0)" ::: "memory"); }
__device__ __forceinline__ int ld_l2_b32_wait(const int* p) {
    int r;
    asm volatile("global_load_dword %0, %1, off sc0\n\t"
                 "s_waitcnt vmcnt(0)"
                 : "=v"(r) : "v"(p) : "memory");
    return r;
}
__device__ __forceinline__ void st_l2_b32(int* p, int v) {
    asm volatile("global_store_dword %0, %1, off sc0" :: "v"(p), "v"(v) : "memory");
}
__device__ __forceinline__ void st_l2_f4(float* p, float4 v) {
    vf4 w; w[0] = v.x; w[1] = v.y; w[2] = v.z; w[3] = v.w;
    asm volatile("global_store_dwordx4 %0, %1, off sc0" :: "v"(p), "v"(w) : "memory");
}
// waits are INSIDE the asm blocks: results are architecturally valid when
// the asm retires, so no consumer can be hoisted above the waitcnt (rule #18).
__device__ __forceinline__ void ld_l2_2xf4(const float* p0, const float* p1,
                                           vf4& a, vf4& b) {
    asm volatile("global_load_dwordx4 %0, %2, off sc0\n\t"
                 "global_load_dwordx4 %1, %3, off sc0\n\t"
                 "s_waitcnt vmcnt(0)"
                 : "=&v"(a), "=&v"(b)
                 : "v"(p0), "v"(p1)
                 : "memory");
}
__device__ __forceinline__ void ld_l2_4xf4(const float* p0, const float* p1,
                                           const float* p2, const float* p3,
                                           vf4& a, vf4& b, vf4& c, vf4& d) {
    asm volatile("global_load_dwordx4 %0, %4, off sc0\n\t"
                 "global_load_dwordx4 %1, %5, off sc0\n\t"
                 "global_load_dwordx4 %2, %6, off sc0\n\t"
                 "global_load_dwordx4 %3, %7, off sc0\n\t"
                 "s_waitcnt vmcnt(0)"
                 : "=&v"(a), "=&v"(b), "=&v"(c), "=&v"(d)
                 : "v"(p0), "v"(p1), "v"(p2), "v"(p3)
                 : "memory");
}

// ---- cross-XCD (coherence-point) wide ops: sc0 sc1 = bypass L1 AND L2 ----
__device__ __forceinline__ void st_cp_f4(float* p, float4 v) {
    vf4 w; w[0] = v.x; w[1] = v.y; w[2] = v.z; w[3] = v.w;
    asm volatile("global_store_dwordx4 %0, %1, off sc0 sc1" :: "v"(p), "v"(w) : "memory");
}
__device__ __forceinline__ void ld_cp_2xf4(const float* p0, const float* p1,
                                           vf4& a, vf4& b) {
    asm volatile("global_load_dwordx4 %0, %2, off sc0 sc1\n\t"
                 "global_load_dwordx4 %1, %3, off sc0 sc1\n\t"
                 "s_waitcnt vmcnt(0)"
                 : "=&v"(a), "=&v"(b)
                 : "v"(p0), "v"(p1)
                 : "memory");
}
__device__ __forceinline__ void ld_cp_4xf4(const float* p0, const float* p1,
                                           const float* p2, const float* p3,
                                           vf4& a, vf4& b, vf4& c, vf4& d) {
    asm volatile("global_load_dwordx4 %0, %4, off sc0 sc1\n\t"
                 "global_load_dwordx4 %1, %5, off sc0 sc1\n\t"
                 "global_load_dwordx4 %2, %6, off sc0 sc1\n\t"
                 "global_load_dwordx4 %3, %7, off sc0 sc1\n\t"
                 "s_waitcnt vmcnt(0)"
                 : "=&v"(a), "=&v"(b), "=&v"(c), "=&v"(d)
                 : "v"(p0), "v"(p1), "v"(p2), "v"(p3)
                 : "memory");
}

__device__ __forceinline__ void wait_flag(int* fp, int tgt, bool fast) {
    if (fast) { while (ld_l2_b32_wait(fp) < tgt) __builtin_amdgcn_s_sleep(1); }
    else      { while (cp_load(fp) < tgt)        __builtin_amdgcn_s_sleep(2); }
}

struct PassArgs {
    const float* wih0; const float* bih0; const float* whh0; const float* bhh0;
    const float* wihA; const float* bihA; const float* whhA; const float* bhhA;
    int firstLayer;
    int NL;
    const float* seqIn;
    long seqTs;
    float* seqOut;
    float* hFinal;
    float* rings;            // [192][DRING][4096]
    int* done;               // [192][FS]
    int* prb;                // [192][FS] probe slots: [0]=val [1]=ready [2]=verdict
};

template<int STACK>
__global__ __launch_bounds__(TPB, 2) void pass_kernel(PassArgs A)
{
    constexpr int NG    = (STACK == 2) ? 96 : 192;   // gate rows per block
    constexpr int NB    = (STACK == 2) ? 128 : 64;   // batch rows per block
    constexpr int KH    = (STACK == 2) ? 128 : 64;   // recurrent K
    constexpr int KI    = (STACK == 2) ? 128 : 64;   // padded input K
    constexpr int PARTS = (STACK == 2) ? 4 : 2;
    constexpr int JS    = NG / 3;
    constexpr int NGG   = NG / 6;
    constexpr int NW    = NGG;                       // row-pair groups per gate
    constexpr int WROW  = NW * 12;                   // packed floats per k-pair

    // packed weights: [k/2][gg][12] = R0 R1 Z0 Z1 N0 N1 (k) | same (k+1)
    __shared__ __align__(16) float wt_hh[(KH / 2) * WROW];
    __shared__ __align__(16) float wt_ih[(KI / 2) * WROW];
    __shared__ __align__(16) float atile[64 * NB];
    __shared__ __align__(16) float hbuf[64 * 64];

    const int tid  = threadIdx.x;

    // layer->blockIdx swizzle: consecutive layers share an XCD under the
    // blockIdx%8 round-robin heuristic.  Pure permutation — correctness is
    // carried by the probes, not by this mapping.
    const int bidx = blockIdx.x;
    int l, part;
    if (STACK == 2) { l = 6  * (bidx & 7) + ((bidx >> 3) >> 2); part = (bidx >> 3) & 3; }
    else            { l = 12 * (bidx & 7) + ((bidx >> 3) >> 1); part = (bidx >> 3) & 1; }
    const int rb = l * PARTS + part;       // logical id: rings/flags/probe index
    const int gl = A.firstLayer + l;

    const int gg = tid & (NGG - 1);
    const int bg = tid / NGG;
    const int jl0 = 2 * gg, jl1 = 2 * gg + 1;
    const int b0 = 4 * bg;

    const float *wih, *bih, *whh, *bhh;
    int din;
    if (gl == 0) { wih = A.wih0; bih = A.bih0; whh = A.whh0; bhh = A.bhh0;
                   din = (STACK == 1) ? 3 : ((STACK == 2) ? 64 : 128); }
    else {
        const int wsz = (STACK == 2) ? 384 * 128 : 192 * 64;
        const int bs  = (STACK == 2) ? 384 : 192;
        wih = A.wihA + (size_t)(gl - 1) * wsz; bih = A.bihA + (size_t)(gl - 1) * bs;
        whh = A.whhA + (size_t)(gl - 1) * wsz; bhh = A.bhhA + (size_t)(gl - 1) * bs;
        din = (STACK == 2) ? 128 : 64;
    }
    const bool wideIH = (STACK == 3) && (gl == 0);

    auto grow = [&](int r) -> int {
        if (STACK == 2) return (r >> 5) * 128 + 32 * part + (r & 31);
        return r;
    };

    // ---- packed weight fills ----
    for (int i = tid; i < NG * KH; i += TPB) {
        int r = i / KH, k = i - r * KH;
        int g = r / JS, j = r - g * JS;
        wt_hh[(k >> 1) * WROW + (j >> 1) * 12 + (k & 1) * 6 + g * 2 + (j & 1)]
            = whh[(size_t)grow(r) * KH + k];
    }
    if (!wideIH) {
        for (int i = tid; i < NG * KI; i += TPB) {
            int r = i / KI, k = i - r * KI;
            int g = r / JS, j = r - g * JS;
            wt_ih[(k >> 1) * WROW + (j >> 1) * 12 + (k & 1) * 6 + g * 2 + (j & 1)]
                = (k < din) ? wih[(size_t)grow(r) * din + k] : 0.0f;
        }
    }

    float bR[2], bZ[2], bNH[2], bNI[2];
#pragma unroll
    for (int jj = 0; jj < 2; ++jj) {
        int jl = jl0 + jj;
        bR[jj]  = bhh[grow(jl)]          + bih[grow(jl)];
        bZ[jj]  = bhh[grow(JS + jl)]     + bih[grow(JS + jl)];
        bNH[jj] = bhh[grow(2 * JS + jl)];
        bNI[jj] = bih[grow(2 * JS + jl)];
    }

    float hprev[2][4];
#pragma unroll
    for (int jj = 0; jj < 2; ++jj)
#pragma unroll
        for (int bb = 0; bb < 4; ++bb) hprev[jj][bb] = 0.0f;

    // ---------------- one-time L2-sharing probes + link modes ----------------
    bool f_in = false, f_out = false, f_fl_self = false, f_fl_par = false, f_fl_child = false;
    {
        int* hsk = (int*)atile;          // scratch; atile unused until t-loop
        const int NL = A.NL;
        if (STACK != 2) {
            // pair (l, l+1) same part; probe slot index = producer rb.
            if (tid == 0 && l < NL - 1) {                        // producer
                int* rg = A.prb + (size_t)rb * FS;
                cp_store(rg, PROBE_A); vmwait0();
                (void)ld_l2_b32_wait(rg);                        // allocate A in my L2
                cp_store(rg, PROBE_B); vmwait0();                // memory := B, L2 keeps A
                cp_store(rg + 1, 1);                             // ready
            }
            if (tid == 1 && l > 0) {                             // consumer of pair (l-1,l)
                int* rg = A.prb + (size_t)((l - 1) * PARTS + part) * FS;
                (void)cp_poll_nz(rg + 1);
                int v = ld_l2_b32_wait(rg);
                cp_store(rg + 2, (v == PROBE_A) ? 2 : 1);        // A => shared L2
            }
            if (tid >= 8 && tid < 12) {                          // gather PP(l-2..l+1)
                int j = l - 2 + (tid - 8);
                hsk[tid - 8] = (j >= 0 && j < NL - 1)
                    ? cp_poll_nz(A.prb + (size_t)(j * PARTS + part) * FS + 2) : 0;
            }
        } else {
            // sibling probes (l,0)->(l,p) at slot l*4+p (p=1..3);
            // inter-layer probe (l,0)->(l+1,0) at slot l*4+0.
            if (part == 0 && tid < 4 && (tid > 0 || l < NL - 1)) {
                int* rg = A.prb + (size_t)(l * 4 + tid) * FS;
                cp_store(rg, PROBE_A); vmwait0();
                (void)ld_l2_b32_wait(rg);
                cp_store(rg, PROBE_B); vmwait0();
                cp_store(rg + 1, 1);
            }
            if (tid == 4 && (part != 0 || l > 0)) {
                int* rg = (part != 0) ? A.prb + (size_t)(l * 4 + part) * FS
                                      : A.prb + (size_t)((l - 1) * 4) * FS;
                (void)cp_poll_nz(rg + 1);
                int v = ld_l2_b32_wait(rg);
                cp_store(rg + 2, (v == PROBE_A) ? 2 : 1);
            }
            if (tid >= 8 && tid < 28) {                          // layers l-2..l+2 x parts
                int q = tid - 8, r = q >> 2, p = q & 3;
                int a = l - 2 + r;
                bool valid = (a >= 0 && a < NL) && (p > 0 || a < NL - 1);
                hsk[q] = valid ? cp_poll_nz(A.prb + (size_t)(a * 4 + p) * FS + 2) : 0;
            }
        }
        __syncthreads();
        if (STACK != 2) {
            const int NLl = A.NL;
            bool pp0 = hsk[0] == 2, pp1 = hsk[1] == 2, pp2 = hsk[2] == 2, pp3 = hsk[3] == 2;
            f_in       = (l > 0) && pp1;
            f_out      = (l == NLl - 1) || pp2;
            f_fl_self  = (l == 0 || pp1) && (l == NLl - 1 || pp2);
            f_fl_par   = (l > 0) && pp1 && (l < 2 || pp0);
            f_fl_child = (l < NLl - 1) && pp2 && (l + 2 >= NLl || pp3);
        } else {
            const int NLl = A.NL;
            bool S[5], T[4];
#pragma unroll
            for (int r = 0; r < 5; ++r)
                S[r] = hsk[r * 4 + 1] == 2 && hsk[r * 4 + 2] == 2 && hsk[r * 4 + 3] == 2;
#pragma unroll
            for (int r = 0; r < 4; ++r) T[r] = hsk[r * 4 + 0] == 2;
            f_out      = S[2] && (l == NLl - 1 || (S[3] && T[2]));
            f_in       = (l > 0) && S[1] && S[2] && T[1];
            f_fl_self  = S[2] && (l == 0 || (S[1] && T[1])) && (l == NLl - 1 || (S[3] && T[2]));
            f_fl_par   = (l > 0) && S[1] && S[2] && T[1] && (l < 2 || (S[0] && T[0]));
            f_fl_child = (l < NLl - 1) && S[2] && S[3] && T[2] && (l + 2 >= NLl || (S[4] && T[3]));
        }
        __syncthreads();
    }

    // packed gemm: 32 k-pairs = 64 k per call.  Per k2: 3x ds_read_b128
    // weights + 2x ds_read_b128 activations, 48 FMA.
    auto gemmP = [&](const float* wt, const float* at, int astride,
                     float (&accR)[2][4], float (&accZ)[2][4], float (&accN)[2][4]) {
#pragma unroll 2
        for (int k2 = 0; k2 < 32; ++k2) {
            const float* wr = wt + k2 * WROW + gg * 12;
            vf4 q0 = *(const vf4*)(wr);          // R0 R1 Z0 Z1   (k even)
            vf4 q1 = *(const vf4*)(wr + 4);      // N0 N1 R0' R1'
            vf4 q2 = *(const vf4*)(wr + 8);      // Z0' Z1' N0' N1' (k odd)
            const float* ar = at + (2 * k2) * astride + b0;
            float4 a0v = *(const float4*)(ar);
            float4 a1v = *(const float4*)(ar + astride);
            float a0[4] = {a0v.x, a0v.y, a0v.z, a0v.w};
            float a1[4] = {a1v.x, a1v.y, a1v.z, a1v.w};
#pragma unroll
            for (int bb = 0; bb < 4; ++bb) {
                accR[0][bb] += q0.x * a0[bb];  accR[1][bb] += q0.y * a0[bb];
                accZ[0][bb] += q0.z * a0[bb];  accZ[1][bb] += q0.w * a0[bb];
                accN[0][bb] += q1.x * a0[bb];  accN[1][bb] += q1.y * a0[bb];
                accR[0][bb] += q1.z * a1[bb];  accR[1][bb] += q1.w * a1[bb];
                accZ[0][bb] += q2.x * a1[bb];  accZ[1][bb] += q2.y * a1[bb];
                accN[0][bb] += q2.z * a1[bb];  accN[1][bb] += q2.w * a1[bb];
            }
        }
    };

    // STACK2 ring staging (4096 floats per kt, 128-wide rows); identical
    // addressing for fast/slow, only cache-policy bits differ.
    auto stage2 = [&](int baseBlk, int slotT, int kt, bool fast) {
        const float* p[4];
#pragma unroll
        for (int q = 0; q < 4; ++q) {
            int u4 = tid + q * TPB, r = u4 >> 5, c4 = u4 & 31, kk = kt * 64 + r;
            p[q] = A.rings + ((size_t)(baseBlk + (kk >> 5)) * DRING + slotT) * 4096
                           + (kk & 31) * 128 + 4 * c4;
        }
        vf4 ta, tb, tc, td;
        if (fast) ld_l2_4xf4(p[0], p[1], p[2], p[3], ta, tb, tc, td);
        else      ld_cp_4xf4(p[0], p[1], p[2], p[3], ta, tb, tc, td);
        {
            int u4, r, c4;
            u4 = tid;           r = u4 >> 5; c4 = u4 & 31; *(vf4*)&atile[r * 128 + 4 * c4] = ta;
            u4 = tid + TPB;     r = u4 >> 5; c4 = u4 & 31; *(vf4*)&atile[r * 128 + 4 * c4] = tb;
            u4 = tid + 2 * TPB; r = u4 >> 5; c4 = u4 & 31; *(vf4*)&atile[r * 128 + 4 * c4] = tc;
            u4 = tid + 3 * TPB; r = u4 >> 5; c4 = u4 & 31; *(vf4*)&atile[r * 128 + 4 * c4] = td;
        }
    };

    for (int t = 0; t < 96; ++t) {
        float accR[2][4] = {}, accZ[2][4] = {}, accNH[2][4] = {}, accNI[2][4] = {};

        if (STACK != 2) {
            // ---- hh first (own LDS state; hides parent flag RTT) ----
            if (t > 0) gemmP(wt_hh, hbuf, 64, accR, accZ, accNH);

            // ---- parent(t) + child-antidep waits ----
            if (tid < 8) {
                int grp = tid >> 2, idx = tid & 3;
                int* fp = nullptr; int tgt = 0; bool fm = false;
                if (grp == 0) { if (l > 0 && idx == part)
                                { fp = &A.done[((l - 1) * PARTS + idx) * FS]; tgt = t + 1; fm = f_fl_par; } }
                else          { if (t >= DRING && l < A.NL - 1 && idx == part)
                                { fp = &A.done[((l + 1) * PARTS + idx) * FS]; tgt = t - DRING + 1; fm = f_fl_child; } }
                if (fp) wait_flag(fp, tgt, fm);
            }
            __syncthreads();

            // ---- ih: stage + gemm ----
            const int nkt = wideIH ? 2 : 1;
            for (int kt = 0; kt < nkt; ++kt) {
                if (kt) __syncthreads();
                if (wideIH) {
                    for (int i = tid; i < 192 * 64; i += TPB) {
                        int r = i >> 6, k = i & 63;
                        int g = r >> 6, j = r & 63;
                        wt_ih[(k >> 1) * WROW + (j >> 1) * 12 + (k & 1) * 6 + g * 2 + (j & 1)]
                            = wih[(size_t)r * 128 + kt * 64 + k];
                    }
                }
                if (l == 0) {
                    const float* src = A.seqIn + (size_t)t * A.seqTs + (size_t)kt * 64 * 128 + 64 * part;
                    for (int i = tid; i < 1024; i += TPB) {
                        int r = i >> 4, seg = i & 15;
                        *(float4*)&atile[r * 64 + seg * 4] = *(const float4*)(src + r * 128 + seg * 4);
                    }
                } else {
                    const float* slot = A.rings + ((size_t)((l - 1) * PARTS + part) * DRING + (t & 3)) * 4096;
                    vf4 ta, tb;
                    if (f_in) ld_l2_2xf4(slot + 4 * tid, slot + 4 * (tid + TPB), ta, tb);
                    else      ld_cp_2xf4(slot + 4 * tid, slot + 4 * (tid + TPB), ta, tb);
                    *(vf4*)&atile[4 * tid] = ta;
                    *(vf4*)&atile[4 * (tid + TPB)] = tb;
                }
                __syncthreads();
                gemmP(wt_ih, atile, 64, accR, accZ, accNI);
            }
        } else {
            // ---- STACK 2: sibling wait + hh from rings ----
            if (t > 0) {
                if (tid < 4 && tid != part)
                    wait_flag(&A.done[(l * 4 + tid) * FS], t, f_fl_self);
                __syncthreads();
                for (int kt = 0; kt < 2; ++kt) {
                    if (kt) __syncthreads();
                    stage2(l * 4, (t - 1) & 3, kt, f_out);
                    __syncthreads();
                    gemmP(wt_hh + kt * 32 * WROW, atile, 128, accR, accZ, accNH);
                }
            }

            // ---- parent + child waits ----
            if (tid < 8) {
                int grp = tid >> 2, idx = tid & 3;
                int* fp = nullptr; int tgt = 0; bool fm = false;
                if (grp == 0) { if (l > 0) { fp = &A.done[((l - 1) * 4 + idx) * FS]; tgt = t + 1; fm = f_fl_par; } }
                else          { if (t >= DRING && l < A.NL - 1)
                                { fp = &A.done[((l + 1) * 4 + idx) * FS]; tgt = t - DRING + 1; fm = f_fl_child; } }
                if (fp) wait_flag(fp, tgt, fm);
            }
            __syncthreads();

            // ---- ih: stage + gemm ----
            const int nkt = (l == 0 && A.firstLayer == 0) ? 1 : 2;
            for (int kt = 0; kt < nkt; ++kt) {
                if (kt) __syncthreads();
                if (l == 0) {
                    const float* src = A.seqIn + (size_t)t * A.seqTs + (size_t)kt * 64 * 128;
                    for (int i = tid; i < 2048; i += TPB)
                        *(float4*)&atile[4 * i] = *(const float4*)(src + 4 * i);
                } else {
                    stage2((l - 1) * 4, t & 3, kt, f_in);
                }
                __syncthreads();
                gemmP(wt_ih + kt * 32 * WROW, atile, 128, accR, accZ, accNI);
            }
        }

        // ---- gates + h update + publish ----
        float4 hv[2];
#pragma unroll
        for (int jj = 0; jj < 2; ++jj) {
            float* hp = (float*)&hv[jj];
#pragma unroll
            for (int bb = 0; bb < 4; ++bb) {
                float r = sigmoid_f(accR[jj][bb] + bR[jj]);
                float z = sigmoid_f(accZ[jj][bb] + bZ[jj]);
                float n = tanh_f(accNI[jj][bb] + bNI[jj] + r * (accNH[jj][bb] + bNH[jj]));
                float h = (1.0f - z) * n + z * hprev[jj][bb];
                hprev[jj][bb] = h;
                hp[bb] = h;
            }
        }
        float* slot = A.rings + ((size_t)rb * DRING + (t & 3)) * 4096;
        if (STACK == 2) {
            if (f_out) {
                st_l2_f4(&slot[jl0 * 128 + b0], hv[0]);
                st_l2_f4(&slot[jl1 * 128 + b0], hv[1]);
            } else {
                st_cp_f4(&slot[jl0 * 128 + b0], hv[0]);
                st_cp_f4(&slot[jl1 * 128 + b0], hv[1]);
            }
            if (A.seqOut && l == A.NL - 1) {
                *(float4*)&A.seqOut[(size_t)t * 16384 + (32 * part + jl0) * 128 + b0] = hv[0];
                *(float4*)&A.seqOut[(size_t)t * 16384 + (32 * part + jl1) * 128 + b0] = hv[1];
            }
        } else {
            if (f_out) {
                st_l2_f4(&slot[jl0 * 64 + b0], hv[0]);
                st_l2_f4(&slot[jl1 * 64 + b0], hv[1]);
            } else {
                st_cp_f4(&slot[jl0 * 64 + b0], hv[0]);
                st_cp_f4(&slot[jl1 * 64 + b0], hv[1]);
            }
            *(float4*)&hbuf[jl0 * 64 + b0] = hv[0];
            *(float4*)&hbuf[jl1 * 64 + b0] = hv[1];
            if (A.seqOut && l == A.NL - 1) {
                *(float4*)&A.seqOut[(size_t)t * 16384 + jl0 * 128 + 64 * part + b0] = hv[0];
                *(float4*)&A.seqOut[(size_t)t * 16384 + jl1 * 128 + 64 * part + b0] = hv[1];
            }
            if (STACK == 3 && l == A.NL - 1 && t == 95 && A.hFinal) {
                *(float4*)&A.hFinal[jl0 * 128 + 64 * part + b0] = hv[0];
                *(float4*)&A.hFinal[jl1 * 128 + 64 * part + b0] = hv[1];
            }
        }
        // explicit per-wave drain (covers the asm sc0/sc1 stores the compiler
        // doesn't track) + barrier => all ring stores visible at their
        // serialization point (shared L2 for fast links, CP for slow) before
        // the flag store below.
        vmwait0();
        __syncthreads();
        if (tid == 0) {
            if (f_fl_self) st_l2_b32(&A.done[rb * FS], t + 1);
            else           cp_store(&A.done[rb * FS], t + 1);
        }
    }
}

__global__ void xprep_kernel(const float* __restrict__ x, float* __restrict__ seqA)
{
    int i = blockIdx.x * 256 + threadIdx.x;
    if (i < 128 * 96 * 3) {
        int b = i / 288, r = i - b * 288;
        int t = r / 3, k = r - 3 * t;
        seqA[(size_t)t * 8192 + k * 128 + b] = x[i];
    }
}

__global__ __launch_bounds__(256) void head_kernel(
    const float* __restrict__ hF,
    const float* __restrict__ d1w, const float* __restrict__ d1b,
    const float* __restrict__ d2w, const float* __restrict__ d2b,
    const float* __restrict__ d3w, const float* __restrict__ d3b,
    float* __restrict__ out)
{
    const int b = blockIdx.x, tid = threadIdx.x;
    __shared__ float h1[64], h2[32];
    if (tid < 64) {
        float s = d1b[tid];
        for (int k = 0; k < 64; ++k) s += d1w[tid * 64 + k] * hF[k * 128 + b];
        h1[tid] = fmaxf(s, 0.0f);
    }
    __syncthreads();
    if (tid < 32) {
        float s = d2b[tid];
        for (int k = 0; k < 64; ++k) s += d2w[tid * 64 + k] * h1[k];
        h2[tid] = fmaxf(s, 0.0f);
    }
    __syncthreads();
    if (tid < 250) {
        float s = d3b[tid];
        for (int k = 0; k < 32; ++k) s += d3w[tid * 32 + k] * h2[k];
        out[b * 250 + tid] = fmaxf(s, 0.0f);
    }
}

extern "C" void kernel_launch(void* const* d_in, const int* in_sizes, int n_in,
                              void* d_out, int out_size, void* d_ws, size_t ws_size,
                              hipStream_t stream)
{
    const float* x       = (const float*)d_in[0];
    const float* g1_wih0 = (const float*)d_in[1];  const float* g1_bih0 = (const float*)d_in[2];
    const float* g1_whh0 = (const float*)d_in[3];  const float* g1_bhh0 = (const float*)d_in[4];
    const float* g1_wih  = (const float*)d_in[5];  const float* g1_bih  = (const float*)d_in[6];
    const float* g1_whh  = (const float*)d_in[7];  const float* g1_bhh  = (const float*)d_in[8];
    const float* g2_wih0 = (const float*)d_in[9];  const float* g2_bih0 = (const float*)d_in[10];
    const float* g2_whh0 = (const float*)d_in[11]; const float* g2_bhh0 = (const float*)d_in[12];
    const float* g2_wih  = (const float*)d_in[13]; const float* g2_bih  = (const float*)d_in[14];
    const float* g2_whh  = (const float*)d_in[15]; const float* g2_bhh  = (const float*)d_in[16];
    const float* g3_wih0 = (const float*)d_in[17]; const float* g3_bih0 = (const float*)d_in[18];
    const float* g3_whh0 = (const float*)d_in[19]; const float* g3_bhh0 = (const float*)d_in[20];
    const float* g3_wih  = (const float*)d_in[21]; const float* g3_bih  = (const float*)d_in[22];
    const float* g3_whh  = (const float*)d_in[23]; const float* g3_bhh  = (const float*)d_in[24];
    const float* d1w = (const float*)d_in[25]; const float* d1b = (const float*)d_in[26];
    const float* d2w = (const float*)d_in[27]; const float* d2b = (const float*)d_in[28];
    const float* d3w = (const float*)d_in[29]; const float* d3b = (const float*)d_in[30];

    float* wsf = (float*)d_ws;
    const size_t RINGS = (size_t)192 * DRING * 4096;
    const size_t B1SZ  = (size_t)96 * 128 * 128;
    const size_t SEQA  = (size_t)96 * 64 * 128;
    const int    SLOTN = 192 * FS;               // ints per pass (flags or probes)
    float* rings  = wsf;
    float* B1     = rings + RINGS;
    float* B2     = B1 + B1SZ;
    float* seqA   = B2 + B1SZ;
    float* hFinal = seqA + SEQA;
    int*   flags  = (int*)(hFinal + 8192);
    int*   prb    = flags + (size_t)4 * SLOTN;

    size_t zero_bytes = (B1SZ * 2 + SEQA + 8192) * sizeof(float)
                      + (size_t)8 * SLOTN * sizeof(int);
    (void)hipMemsetAsync(B1, 0, zero_bytes, stream);

    xprep_kernel<<<dim3(144), dim3(256), 0, stream>>>(x, seqA);

    PassArgs P;
    P = {g1_wih0, g1_bih0, g1_whh0, g1_bhh0, g1_wih, g1_bih, g1_whh, g1_bhh,
         0, 96, seqA, 8192, B1, nullptr, rings, flags + 0 * SLOTN, prb + 0 * SLOTN};
    pass_kernel<1><<<dim3(192), dim3(TPB), 0, stream>>>(P);

    P = {g2_wih0, g2_bih0, g2_whh0, g2_bhh0, g2_wih, g2_bih, g2_whh, g2_bhh,
         0, 48, B1, 16384, B2, nullptr, rings, flags + 1 * SLOTN, prb + 1 * SLOTN};
    pass_kernel<2><<<dim3(192), dim3(TPB), 0, stream>>>(P);

    P = {g2_wih0, g2_bih0, g2_whh0, g2_bhh0, g2_wih, g2_bih, g2_whh, g2_bhh,
         48, 48, B2, 16384, B1, nullptr, rings, flags + 2 * SLOTN, prb + 2 * SLOTN};
    pass_kernel<2><<<dim3(192), dim3(TPB), 0, stream>>>(P);

    P = {g3_wih0, g3_bih0, g3_whh0, g3_bhh0, g3_wih, g3_bih, g3_whh, g3_bhh,
         0, 96, B1, 16384, nullptr, hFinal, rings, flags + 3 * SLOTN, prb + 3 * SLOTN};
    pass_kernel<3><<<dim3(192), dim3(TPB), 0, stream>>>(P);

    head_kernel<<<dim3(128), dim3(256), 0, stream>>>(hFinal, d1w, d1b, d2w, d2b, d3w, d3b,
                                                     (float*)d_out);
}